// Round 5
// baseline (41.078 us; speedup 1.0000x reference)
//
#include <hip/hip_runtime.h>
#include <stdint.h>

#define BATCH 64
#define MDIM 512
#define NDIM 512
#define KDIM 256
#define BM 128
#define BN 128
#define BK 32
#define NKSTEP 8    // KDIM / BK
#define NTILES 16   // (512/128)^2
#define LDSW 40     // 32 data + 8 pad shorts -> 80B row stride (16B-aligned)

typedef __attribute__((ext_vector_type(8))) short short8;
typedef __attribute__((ext_vector_type(4))) float f32x4;
typedef __attribute__((ext_vector_type(4))) unsigned int u32x4;

// HW packed f32->bf16 RNE (no builtin on gfx950; single instr)
__device__ __forceinline__ unsigned int cvt_pk(float lo, float hi) {
  unsigned int r;
  asm("v_cvt_pk_bf16_f32 %0, %1, %2" : "=v"(r) : "v"(lo), "v"(hi));
  return r;
}

// Raw barrier: waits LDS ops only; global loads stay in flight.
#define BARRIER()                                         \
  {                                                       \
    asm volatile("s_waitcnt lgkmcnt(0)" ::: "memory");    \
    __builtin_amdgcn_s_barrier();                         \
    asm volatile("" ::: "memory");                        \
  }

__device__ __forceinline__ float waveRedSum(float v) {
  v += __shfl_xor(v, 32);
  v += __shfl_xor(v, 16);
  v += __shfl_xor(v, 8);
  v += __shfl_xor(v, 4);
  v += __shfl_xor(v, 2);
  v += __shfl_xor(v, 1);
  return v;
}

// 256 threads = 4 waves (2x2 grid); block = 128x128 tile; wave tile 64x64.
// acc = 16 frags (64 VGPR); LDS fragment traffic 0.031 B/FLOP.
__global__ __launch_bounds__(256, 3) void pot_gemm_reduce(
    const float* __restrict__ V, const float* __restrict__ A,
    float* __restrict__ part) {
  const int bid = blockIdx.x;
  const int lin = (bid & 7) * 128 + (bid >> 3);   // XCD swizzle (1024%8==0)
  const int b   = lin >> 4;
  const int t   = lin & 15;
  const int tm  = t >> 2;
  const int tn  = t & 3;

  const int tid   = threadIdx.x;   // 0..255
  const int w     = tid >> 6;      // wave 0..3
  const int lane  = tid & 63;
  const int wr    = w >> 1;        // 0..1 : 64-row strip
  const int wc    = w & 1;         // 0..1 : 64-col strip
  const int srow  = tid >> 1;      // staging row 0..127
  const int shalf = tid & 1;       // which 16-float half of the 32-wide K slab

  __shared__ short As[2][BM][LDSW];
  __shared__ short Bs[2][BN][LDSW];
  __shared__ float nvs[BM];
  __shared__ float nas[BN];
  __shared__ float red[4][4];

  const float* Vg = V + ((size_t)b * MDIM + (size_t)tm * BM + srow) * KDIM + shalf * 16;
  const float* Ag = A + ((size_t)b * NDIM + (size_t)tn * BN + srow) * KDIM + shalf * 16;

  float sqa = 0.f, sqb = 0.f;
  f32x4 acc[4][4];
#pragma unroll
  for (int m = 0; m < 4; ++m)
#pragma unroll
    for (int n = 0; n < 4; ++n)
      acc[m][n] = (f32x4){0.f, 0.f, 0.f, 0.f};

  float4 ra[4], rb[4];   // 16 floats of A + 16 of B per k-step (1-deep)

#define ISSUE(k)                                                              \
  {                                                                           \
    const float4* pa = reinterpret_cast<const float4*>(Vg + (k) * BK);        \
    const float4* pb = reinterpret_cast<const float4*>(Ag + (k) * BK);        \
    ra[0] = pa[0]; ra[1] = pa[1]; ra[2] = pa[2]; ra[3] = pa[3];               \
    rb[0] = pb[0]; rb[1] = pb[1]; rb[2] = pb[2]; rb[3] = pb[3];               \
  }

#define SQ4(s_, f) { s_ += (f).x*(f).x + (f).y*(f).y + (f).z*(f).z + (f).w*(f).w; }

#define WRITE(buf)                                                            \
  {                                                                           \
    u32x4 wa0, wa1, wb0, wb1;                                                 \
    wa0[0] = cvt_pk(ra[0].x, ra[0].y); wa0[1] = cvt_pk(ra[0].z, ra[0].w);     \
    wa0[2] = cvt_pk(ra[1].x, ra[1].y); wa0[3] = cvt_pk(ra[1].z, ra[1].w);     \
    wa1[0] = cvt_pk(ra[2].x, ra[2].y); wa1[1] = cvt_pk(ra[2].z, ra[2].w);     \
    wa1[2] = cvt_pk(ra[3].x, ra[3].y); wa1[3] = cvt_pk(ra[3].z, ra[3].w);     \
    wb0[0] = cvt_pk(rb[0].x, rb[0].y); wb0[1] = cvt_pk(rb[0].z, rb[0].w);     \
    wb0[2] = cvt_pk(rb[1].x, rb[1].y); wb0[3] = cvt_pk(rb[1].z, rb[1].w);     \
    wb1[0] = cvt_pk(rb[2].x, rb[2].y); wb1[1] = cvt_pk(rb[2].z, rb[2].w);     \
    wb1[2] = cvt_pk(rb[3].x, rb[3].y); wb1[3] = cvt_pk(rb[3].z, rb[3].w);     \
    SQ4(sqa, ra[0]); SQ4(sqa, ra[1]); SQ4(sqa, ra[2]); SQ4(sqa, ra[3]);       \
    SQ4(sqb, rb[0]); SQ4(sqb, rb[1]); SQ4(sqb, rb[2]); SQ4(sqb, rb[3]);       \
    *reinterpret_cast<u32x4*>(&As[buf][srow][shalf * 16 + 0]) = wa0;          \
    *reinterpret_cast<u32x4*>(&As[buf][srow][shalf * 16 + 8]) = wa1;          \
    *reinterpret_cast<u32x4*>(&Bs[buf][srow][shalf * 16 + 0]) = wb0;          \
    *reinterpret_cast<u32x4*>(&Bs[buf][srow][shalf * 16 + 8]) = wb1;          \
  }

#define COMPUTE(buf)                                                          \
  {                                                                           \
    short8 af[4], bf[4];                                                      \
    const int fr   = lane & 15;                                               \
    const int koff = (lane >> 4) * 8;                                         \
    _Pragma("unroll")                                                         \
    for (int m = 0; m < 4; ++m)                                               \
      af[m] = *reinterpret_cast<const short8*>(                               \
          &As[buf][wr * 64 + m * 16 + fr][koff]);                             \
    _Pragma("unroll")                                                         \
    for (int n = 0; n < 4; ++n)                                               \
      bf[n] = *reinterpret_cast<const short8*>(                               \
          &Bs[buf][wc * 64 + n * 16 + fr][koff]);                             \
    _Pragma("unroll")                                                         \
    for (int m = 0; m < 4; ++m)                                               \
      _Pragma("unroll")                                                       \
      for (int n = 0; n < 4; ++n)                                             \
        acc[m][n] = __builtin_amdgcn_mfma_f32_16x16x32_bf16(                  \
            af[m], bf[n], acc[m][n], 0, 0, 0);                                \
  }

  // prologue
  ISSUE(0);
  WRITE(0);
  BARRIER();

#pragma unroll
  for (int k = 0; k < NKSTEP; ++k) {
    if (k + 1 < NKSTEP) ISSUE(k + 1);        // loads in flight over COMPUTE
    COMPUTE(k & 1);
    if (k + 1 < NKSTEP) WRITE((k + 1) & 1);  // cvt+ds_write after compute
    BARRIER();
  }

  // half-norms 0.5*||row||^2 (row split across lane pairs via shalf)
  {
    float va = sqa + __shfl_xor(sqa, 1);
    float vb = sqb + __shfl_xor(sqb, 1);
    if (shalf == 0) { nvs[srow] = 0.5f * va; nas[srow] = 0.5f * vb; }
  }
  BARRIER();

  // epilogue: hoist norms to registers, then C = hr + hc - dot; T = 2^(C*k2)
  float hr[4][4], hc[4];
#pragma unroll
  for (int m = 0; m < 4; ++m)
#pragma unroll
    for (int r = 0; r < 4; ++r)
      hr[m][r] = nvs[wr * 64 + m * 16 + (lane >> 4) * 4 + r];
#pragma unroll
  for (int n = 0; n < 4; ++n)
    hc[n] = nas[wc * 64 + n * 16 + (lane & 15)];

  const bool rowmask = (tm == 0) && (wr == 0) && ((lane >> 4) == 0);
  const bool colmask = (tn == 0) && (wc == 0) && ((lane & 15) == 0);
  const float k2 = -1.0e-3f * 1.4426950408889634f;  // -1/beta * log2(e)

  float s0p = 0.f, ctp = 0.f, rsp = 0.f, csp = 0.f;
#pragma unroll
  for (int m = 0; m < 4; ++m) {
#pragma unroll
    for (int n = 0; n < 4; ++n) {
#pragma unroll
      for (int r = 0; r < 4; ++r) {
        float Cv = hr[m][r] + hc[n] - acc[m][n][r];
        float T = exp2f(Cv * k2);
        s0p += T;
        ctp += Cv * T;
        if (m == 0 && r == 0) rsp += rowmask ? T : 0.f;  // global row 0
        if (n == 0)           csp += colmask ? T : 0.f;  // global col 0
      }
    }
  }

  s0p = waveRedSum(s0p);
  ctp = waveRedSum(ctp);
  rsp = waveRedSum(rsp);
  csp = waveRedSum(csp);
  if (lane == 0) { red[w][0] = s0p; red[w][1] = ctp; red[w][2] = rsp; red[w][3] = csp; }
  BARRIER();
  if (tid == 0) {
    float s0 = 0.f, ct = 0.f, rs = 0.f, cs = 0.f;
#pragma unroll
    for (int i = 0; i < 4; ++i) {
      s0 += red[i][0]; ct += red[i][1]; rs += red[i][2]; cs += red[i][3];
    }
    float* p = part + ((size_t)(b * NTILES + t)) * 4;
    p[0] = s0; p[1] = ct; p[2] = rs; p[3] = cs;
  }
}

// One wave; thread b = batch b: deterministic tile reduce + 10-iter scalar
// recurrence + batch mean.
__global__ __launch_bounds__(64) void pot_finalize(
    const float* __restrict__ part, float* __restrict__ out) {
  const int b = threadIdx.x;
  float S0 = 0.f, CT = 0.f, RS = 0.f, CS = 0.f;
#pragma unroll
  for (int t = 0; t < NTILES; ++t) {
    const float* p = part + ((size_t)(b * NTILES + t)) * 4;
    S0 += p[0]; CT += p[1]; RS += p[2]; CS += p[3];
  }
  const float a0 = 1.0f / (float)MDIM;
  const float b0 = 1.0f / (float)NDIM;
  const float s  = (float)MDIM;
  float c = s / S0;
#pragma unroll
  for (int i = 0; i < 10; ++i) {
    float ka = fminf(a0 / (c * RS), 1.0f);
    float kb = fminf(b0 / (ka * c * CS), 1.0f);
    c = s * ka * kb / S0;
  }
  float D = c * CT;
  D = waveRedSum(D);
  if (b == 0) out[0] = D * (1.0f / (float)BATCH);
}

extern "C" void kernel_launch(void* const* d_in, const int* in_sizes, int n_in,
                              void* d_out, int out_size, void* d_ws, size_t ws_size,
                              hipStream_t stream) {
  const float* V = (const float*)d_in[0];   // v_emb [64,512,256] f32
  const float* A = (const float*)d_in[1];   // a_emb [64,512,256] f32
  float* out = (float*)d_out;
  float* part = (float*)d_ws;               // [64][16][4] f32 partials

  pot_gemm_reduce<<<dim3(BATCH * NTILES), 256, 0, stream>>>(V, A, part);
  pot_finalize<<<1, 64, 0, stream>>>(part, out);
}

// Round 6
// 29.957 us; speedup vs baseline: 1.3713x; 1.3713x over previous
//
#include <hip/hip_runtime.h>
#include <stdint.h>

#define BATCH 64
#define MDIM 512
#define NDIM 512
#define KDIM 256
#define BM 128
#define BN 128
#define BK 32
#define NKSTEP 8    // KDIM / BK
#define NTILES 16   // (512/128)^2
#define LDSW 32     // no pad; conflicts handled by XOR swizzle of 16B units

typedef __attribute__((ext_vector_type(8))) short short8;
typedef __attribute__((ext_vector_type(4))) float f32x4;
typedef __attribute__((ext_vector_type(4))) unsigned int u32x4;

// HW packed f32->bf16 RNE (no builtin on gfx950; single instr)
__device__ __forceinline__ unsigned int cvt_pk(float lo, float hi) {
  unsigned int r;
  asm("v_cvt_pk_bf16_f32 %0, %1, %2" : "=v"(r) : "v"(lo), "v"(hi));
  return r;
}

// Raw barrier: waits LDS ops only; global loads stay in flight (counted vmcnt).
#define BARRIER()                                         \
  {                                                       \
    asm volatile("s_waitcnt lgkmcnt(0)" ::: "memory");    \
    __builtin_amdgcn_s_barrier();                         \
    asm volatile("" ::: "memory");                        \
  }

__device__ __forceinline__ float waveRedSum(float v) {
  v += __shfl_xor(v, 32);
  v += __shfl_xor(v, 16);
  v += __shfl_xor(v, 8);
  v += __shfl_xor(v, 4);
  v += __shfl_xor(v, 2);
  v += __shfl_xor(v, 1);
  return v;
}

// 512 threads = 8 waves (2x4 grid); block = 128x128 tile; wave tile 64x32.
// LDS unit-swizzle u' = u ^ ((row>>1)&3): conflict-free b128 reads AND writes
// (each 8-lane phase covers all 8 16B bank-groups; bijective within row).
__global__ __launch_bounds__(512, 4) void pot_gemm_reduce(
    const float* __restrict__ V, const float* __restrict__ A,
    float* __restrict__ part) {
  const int bid = blockIdx.x;
  const int lin = (bid & 7) * 128 + (bid >> 3);   // XCD swizzle (1024%8==0)
  const int b   = lin >> 4;
  const int t   = lin & 15;
  const int tm  = t >> 2;
  const int tn  = t & 3;

  const int tid  = threadIdx.x;
  const int w    = tid >> 6;
  const int lane = tid & 63;
  const int wr   = w >> 2;         // 0..1 : 64-row strip
  const int wc   = w & 3;          // 0..3 : 32-col strip
  const int srow = tid >> 2;       // staging row 0..127
  const int sseg = tid & 3;        // staging 16B unit (8 bf16 / 8 fp32-in)
  const int ssw  = (sseg ^ ((srow >> 1) & 3)) * 8;  // swizzled unit offset

  __shared__ short As[2][BM][LDSW];   // 8 KiB each buf per matrix; 32 KiB total
  __shared__ short Bs[2][BN][LDSW];
  __shared__ float nvs[BM];
  __shared__ float nas[BN];
  __shared__ float red[8][4];

  const float* Vg = V + ((size_t)b * MDIM + (size_t)tm * BM + srow) * KDIM + sseg * 8;
  const float* Ag = A + ((size_t)b * NDIM + (size_t)tn * BN + srow) * KDIM + sseg * 8;

  float sqa = 0.f, sqb = 0.f;
  f32x4 acc[4][2];
#pragma unroll
  for (int m = 0; m < 4; ++m)
#pragma unroll
    for (int n = 0; n < 2; ++n)
      acc[m][n] = (f32x4){0.f, 0.f, 0.f, 0.f};

  float4 ra[2][2], rb[2][2];   // 2 prefetch slots x 8 floats per matrix

#define ISSUE(k, slot)                                                        \
  {                                                                           \
    const float4* pa = reinterpret_cast<const float4*>(Vg + (k) * BK);        \
    const float4* pb = reinterpret_cast<const float4*>(Ag + (k) * BK);        \
    ra[slot][0] = pa[0]; ra[slot][1] = pa[1];                                 \
    rb[slot][0] = pb[0]; rb[slot][1] = pb[1];                                 \
  }

#define SQ4(s_, f) { s_ += (f).x*(f).x + (f).y*(f).y + (f).z*(f).z + (f).w*(f).w; }

#define WRITE(buf, slot)                                                      \
  {                                                                           \
    u32x4 wa, wb;                                                             \
    wa[0] = cvt_pk(ra[slot][0].x, ra[slot][0].y);                             \
    wa[1] = cvt_pk(ra[slot][0].z, ra[slot][0].w);                             \
    wa[2] = cvt_pk(ra[slot][1].x, ra[slot][1].y);                             \
    wa[3] = cvt_pk(ra[slot][1].z, ra[slot][1].w);                             \
    wb[0] = cvt_pk(rb[slot][0].x, rb[slot][0].y);                             \
    wb[1] = cvt_pk(rb[slot][0].z, rb[slot][0].w);                             \
    wb[2] = cvt_pk(rb[slot][1].x, rb[slot][1].y);                             \
    wb[3] = cvt_pk(rb[slot][1].z, rb[slot][1].w);                             \
    SQ4(sqa, ra[slot][0]); SQ4(sqa, ra[slot][1]);                             \
    SQ4(sqb, rb[slot][0]); SQ4(sqb, rb[slot][1]);                             \
    *reinterpret_cast<u32x4*>(&As[buf][srow][ssw]) = wa;                      \
    *reinterpret_cast<u32x4*>(&Bs[buf][srow][ssw]) = wb;                      \
  }

#define COMPUTE(buf)                                                          \
  {                                                                           \
    short8 af[4], bf[2];                                                      \
    const int fr  = lane & 15;                                                \
    const int ksw = ((lane >> 4) ^ ((fr >> 1) & 3)) * 8;  /* swizzled read */ \
    _Pragma("unroll")                                                         \
    for (int m = 0; m < 4; ++m)                                               \
      af[m] = *reinterpret_cast<const short8*>(                               \
          &As[buf][wr * 64 + m * 16 + fr][ksw]);                              \
    _Pragma("unroll")                                                         \
    for (int n = 0; n < 2; ++n)                                               \
      bf[n] = *reinterpret_cast<const short8*>(                               \
          &Bs[buf][wc * 32 + n * 16 + fr][ksw]);                              \
    _Pragma("unroll")                                                         \
    for (int m = 0; m < 4; ++m)                                               \
      _Pragma("unroll")                                                       \
      for (int n = 0; n < 2; ++n)                                             \
        acc[m][n] = __builtin_amdgcn_mfma_f32_16x16x32_bf16(                  \
            af[m], bf[n], acc[m][n], 0, 0, 0);                                \
  }

  // prologue: slots 0,1 in flight; buf0 staged
  ISSUE(0, 0);
  ISSUE(1, 1);
  WRITE(0, 0);
  BARRIER();

#pragma unroll
  for (int k = 0; k < NKSTEP; ++k) {
    if (k + 2 < NKSTEP) ISSUE(k + 2, k & 1);      // refill slot just freed
    COMPUTE(k & 1);
    if (k + 1 < NKSTEP) WRITE((k + 1) & 1, (k + 1) & 1);
    BARRIER();          // raw: prefetched loads stay in flight across it
  }

  // half-norms 0.5*||row||^2 : reduce over the 4 sseg lanes of each row quad
  {
    float va = sqa;
    va += __shfl_xor(va, 1); va += __shfl_xor(va, 2);
    float vb = sqb;
    vb += __shfl_xor(vb, 1); vb += __shfl_xor(vb, 2);
    if (sseg == 0) { nvs[srow] = 0.5f * va; nas[srow] = 0.5f * vb; }
  }
  BARRIER();

  // epilogue: hoist norms to registers; C = hr + hc - dot; T = 2^(C*k2)
  float hr[4][4], hc[2];
#pragma unroll
  for (int m = 0; m < 4; ++m)
#pragma unroll
    for (int r = 0; r < 4; ++r)
      hr[m][r] = nvs[wr * 64 + m * 16 + (lane >> 4) * 4 + r];
#pragma unroll
  for (int n = 0; n < 2; ++n)
    hc[n] = nas[wc * 32 + n * 16 + (lane & 15)];

  const bool rowmask = (tm == 0) && (wr == 0) && ((lane >> 4) == 0);
  const bool colmask = (tn == 0) && (wc == 0) && ((lane & 15) == 0);
  const float k2 = -1.0e-3f * 1.4426950408889634f;  // -1/beta * log2(e)

  float s0p = 0.f, ctp = 0.f, rsp = 0.f, csp = 0.f;
#pragma unroll
  for (int m = 0; m < 4; ++m) {
#pragma unroll
    for (int n = 0; n < 2; ++n) {
#pragma unroll
      for (int r = 0; r < 4; ++r) {
        float Cv = hr[m][r] + hc[n] - acc[m][n][r];
        float T = exp2f(Cv * k2);
        s0p += T;
        ctp += Cv * T;
        if (m == 0 && r == 0) rsp += rowmask ? T : 0.f;  // global row 0
        if (n == 0)           csp += colmask ? T : 0.f;  // global col 0
      }
    }
  }

  s0p = waveRedSum(s0p);
  ctp = waveRedSum(ctp);
  rsp = waveRedSum(rsp);
  csp = waveRedSum(csp);
  if (lane == 0) { red[w][0] = s0p; red[w][1] = ctp; red[w][2] = rsp; red[w][3] = csp; }
  BARRIER();
  if (tid == 0) {
    float s0 = 0.f, ct = 0.f, rs = 0.f, cs = 0.f;
#pragma unroll
    for (int i = 0; i < 8; ++i) {
      s0 += red[i][0]; ct += red[i][1]; rs += red[i][2]; cs += red[i][3];
    }
    float* p = part + ((size_t)(b * NTILES + t)) * 4;
    p[0] = s0; p[1] = ct; p[2] = rs; p[3] = cs;
  }
}

// One wave; thread b = batch b: deterministic tile reduce + 10-iter scalar
// recurrence + batch mean.
__global__ __launch_bounds__(64) void pot_finalize(
    const float* __restrict__ part, float* __restrict__ out) {
  const int b = threadIdx.x;
  float S0 = 0.f, CT = 0.f, RS = 0.f, CS = 0.f;
#pragma unroll
  for (int t = 0; t < NTILES; ++t) {
    const float* p = part + ((size_t)(b * NTILES + t)) * 4;
    S0 += p[0]; CT += p[1]; RS += p[2]; CS += p[3];
  }
  const float a0 = 1.0f / (float)MDIM;
  const float b0 = 1.0f / (float)NDIM;
  const float s  = (float)MDIM;
  float c = s / S0;
#pragma unroll
  for (int i = 0; i < 10; ++i) {
    float ka = fminf(a0 / (c * RS), 1.0f);
    float kb = fminf(b0 / (ka * c * CS), 1.0f);
    c = s * ka * kb / S0;
  }
  float D = c * CT;
  D = waveRedSum(D);
  if (b == 0) out[0] = D * (1.0f / (float)BATCH);
}

extern "C" void kernel_launch(void* const* d_in, const int* in_sizes, int n_in,
                              void* d_out, int out_size, void* d_ws, size_t ws_size,
                              hipStream_t stream) {
  const float* V = (const float*)d_in[0];   // v_emb [64,512,256] f32
  const float* A = (const float*)d_in[1];   // a_emb [64,512,256] f32
  float* out = (float*)d_out;
  float* part = (float*)d_ws;               // [64][16][4] f32 partials

  pot_gemm_reduce<<<dim3(BATCH * NTILES), 512, 0, stream>>>(V, A, part);
  pot_finalize<<<1, 64, 0, stream>>>(part, out);
}